// Round 5
// baseline (186.467 us; speedup 1.0000x reference)
//
#include <hip/hip_runtime.h>
#include <hip/hip_fp16.h>

typedef _Float16 f16x8 __attribute__((ext_vector_type(8)));
typedef float    f32x4 __attribute__((ext_vector_type(4)));

#define IMG   512
#define NIMG  64
#define TS_R  32
#define TS_C  64
#define NBLK  (NIMG * (IMG/TS_R) * (IMG/TS_C))   // 8192
#define HST   56     // Ht row stride in halves (112 B: 16B-mult, conflict-free b128 octets)

#define C1F   1.0e-4f
#define C2F   9.0e-4f

__device__ __forceinline__ uint2 cvt4h(f32x4 a) {
    __half2 p0 = __floats2half2_rn(a[0], a[1]);
    __half2 p1 = __floats2half2_rn(a[2], a[3]);
    uint2 r; r.x = *reinterpret_cast<uint*>(&p0); r.y = *reinterpret_cast<uint*>(&p1);
    return r;
}

__device__ __forceinline__ f16x8 to8(float4 a, float4 b) {
    f16x8 r;
    r[0]=(_Float16)a.x; r[1]=(_Float16)a.y; r[2]=(_Float16)a.z; r[3]=(_Float16)a.w;
    r[4]=(_Float16)b.x; r[5]=(_Float16)b.y; r[6]=(_Float16)b.z; r[7]=(_Float16)b.w;
    return r;
}

__global__ __launch_bounds__(256, 4)
void ssim_main(const float* __restrict__ x, const float* __restrict__ y,
               float* __restrict__ partial) {
    // Ht[field][tile_col][h_row] fp16 — the only LDS use. 5*64*56*2 = 35840 B.
    __shared__ __align__(16) __half Ht[5][TS_C][HST];
    __shared__ float red[4];

    const int tid  = threadIdx.x;
    const int lane = tid & 63;
    const int wv   = tid >> 6;       // wave 0..3 -> 16-col output strip
    const int l16  = lane & 15;
    const int g16  = lane >> 4;
    const int n0   = wv * 16;

    // Gaussian taps: w[d] = exp(-(d-5)^2/4.5)/sum, d in [0,10].
    float wsum = 0.0f;
    #pragma unroll
    for (int k = 0; k < 11; ++k) {
        float d = (float)(k - 5);
        wsum += __expf(-d * d * (1.0f / 4.5f));
    }
    const float inv = 1.0f / wsum;

    // Band fragments (lane-only):
    //  H-pass B[k][n] = w(k - n - 3), k=g16*8+j, n=l16  -> d = d0 + j
    //  V-pass A[r][k] = w(k - r),     r=l16, k=g16*8+j  -> d = d0 + j + 3
    const int d0 = g16 * 8 - l16 - 3;
    _Float16 bv[11];
    #pragma unroll
    for (int j = 0; j < 11; ++j) {
        int d = d0 + j;
        float t = (float)(d - 5);
        float v = __expf(-t * t * (1.0f / 4.5f)) * inv;
        bv[j] = ((unsigned)d <= 10u) ? (_Float16)v : (_Float16)0.0f;
    }
    f16x8 WhB, WvA;
    #pragma unroll
    for (int j = 0; j < 8; ++j) WhB[j] = bv[j];
    #pragma unroll
    for (int j = 0; j < 8; ++j) WvA[j] = bv[j + 3];

    const int img = blockIdx.z;
    const int r0  = blockIdx.y * TS_R;
    const int c0  = blockIdx.x * TS_C;
    const float* xb = x + (size_t)img * IMG * IMG;
    const float* yb = y + (size_t)img * IMG * IMG;

    const int hcol = n0 + l16;                // this lane's tile column
    const int wc   = c0 + n0 - 8 + g16 * 8;   // K-window col base for this lane
    const bool okA = (unsigned)wc       <= 508u;   // float4 fully in [0,512)
    const bool okB = (unsigned)(wc + 4) <= 508u;
    const float4 z4 = make_float4(0.f, 0.f, 0.f, 0.f);

    // ---- H pass: 3 row-groups of 16 H-rows; A = image rows (direct global), B = band ----
    #pragma unroll
    for (int mg = 0; mg < 3; ++mg) {
        int  hr  = r0 + mg * 16 + l16 - 5;     // image row for H-row mg*16+l16
        bool rok = (unsigned)hr < (unsigned)IMG;
        const float* xr = xb + (size_t)hr * IMG + wc;
        const float* yr = yb + (size_t)hr * IMG + wc;
        float4 xv0 = (rok && okA) ? *(const float4*)(xr)     : z4;
        float4 xv1 = (rok && okB) ? *(const float4*)(xr + 4) : z4;
        float4 yv0 = (rok && okA) ? *(const float4*)(yr)     : z4;
        float4 yv1 = (rok && okB) ? *(const float4*)(yr + 4) : z4;
        f16x8 xf = to8(xv0, xv1);
        f16x8 yf = to8(yv0, yv1);
        f16x8 xx = xf * xf;
        f16x8 yy = yf * yf;
        f16x8 xy = xf * yf;
        f32x4 z = {0.f, 0.f, 0.f, 0.f};
        f32x4 aX  = __builtin_amdgcn_mfma_f32_16x16x32_f16(xf, WhB, z, 0, 0, 0);
        f32x4 aY  = __builtin_amdgcn_mfma_f32_16x16x32_f16(yf, WhB, z, 0, 0, 0);
        f32x4 aXX = __builtin_amdgcn_mfma_f32_16x16x32_f16(xx, WhB, z, 0, 0, 0);
        f32x4 aYY = __builtin_amdgcn_mfma_f32_16x16x32_f16(yy, WhB, z, 0, 0, 0);
        f32x4 aXY = __builtin_amdgcn_mfma_f32_16x16x32_f16(xy, WhB, z, 0, 0, 0);
        // C layout: col = lane&15 (= output col l16), rows = mg*16 + g16*4 + r.
        int hrow = mg * 16 + g16 * 4;
        *(uint2*)&Ht[0][hcol][hrow] = cvt4h(aX);
        *(uint2*)&Ht[1][hcol][hrow] = cvt4h(aY);
        *(uint2*)&Ht[2][hcol][hrow] = cvt4h(aXX);
        *(uint2*)&Ht[3][hcol][hrow] = cvt4h(aYY);
        *(uint2*)&Ht[4][hcol][hrow] = cvt4h(aXY);
    }
    // No barrier: each wave's V-pass reads only its own 16-col Ht strip (same wave,
    // in-order LDS per wave).

    // ---- V pass + SSIM epilogue: per mt, one K=32 MFMA per field ----
    float ssum = 0.0f;
    #pragma unroll
    for (int mt = 0; mt < 2; ++mt) {
        int ko = mt * 16 + g16 * 8;           // K window = H rows mt*16 .. mt*16+31
        f16x8 b0 = *(const f16x8*)&Ht[0][hcol][ko];
        f16x8 b1 = *(const f16x8*)&Ht[1][hcol][ko];
        f16x8 b2 = *(const f16x8*)&Ht[2][hcol][ko];
        f16x8 b3 = *(const f16x8*)&Ht[3][hcol][ko];
        f16x8 b4 = *(const f16x8*)&Ht[4][hcol][ko];
        f32x4 z = {0.f, 0.f, 0.f, 0.f};
        f32x4 cX  = __builtin_amdgcn_mfma_f32_16x16x32_f16(WvA, b0, z, 0, 0, 0);
        f32x4 cY  = __builtin_amdgcn_mfma_f32_16x16x32_f16(WvA, b1, z, 0, 0, 0);
        f32x4 cXX = __builtin_amdgcn_mfma_f32_16x16x32_f16(WvA, b2, z, 0, 0, 0);
        f32x4 cYY = __builtin_amdgcn_mfma_f32_16x16x32_f16(WvA, b3, z, 0, 0, 0);
        f32x4 cXY = __builtin_amdgcn_mfma_f32_16x16x32_f16(WvA, b4, z, 0, 0, 0);
        #pragma unroll
        for (int r = 0; r < 4; ++r) {
            float mx  = cX[r];
            float my  = cY[r];
            float exx = cXX[r];
            float eyy = cYY[r];
            float exy = cXY[r];
            float mxx = mx * mx, myy = my * my, mxy = mx * my;
            float vx  = exx - mxx;
            float vy  = eyy - myy;
            float vxy = exy - mxy;
            float num = (2.0f * mxy + C1F) * (2.0f * vxy + C2F);
            float den = (mxx + myy + C1F) * (vx + vy + C2F);
            ssum = fmaf(num, __builtin_amdgcn_rcpf(den), ssum);
        }
    }

    // ---- Block reduction (deterministic) ----
    #pragma unroll
    for (int off = 32; off > 0; off >>= 1)
        ssum += __shfl_down(ssum, off, 64);
    if ((tid & 63) == 0) red[tid >> 6] = ssum;
    __syncthreads();
    if (tid == 0) {
        float tot = red[0] + red[1] + red[2] + red[3];
        int bi = (blockIdx.z * gridDim.y + blockIdx.y) * gridDim.x + blockIdx.x;
        partial[bi] = tot;
    }
}

__global__ __launch_bounds__(1024)
void ssim_final(const float* __restrict__ partial, float* __restrict__ out) {
    __shared__ float red[16];
    float s = 0.0f;
    for (int i = threadIdx.x; i < NBLK; i += 1024) s += partial[i];
    #pragma unroll
    for (int off = 32; off > 0; off >>= 1)
        s += __shfl_down(s, off, 64);
    if ((threadIdx.x & 63) == 0) red[threadIdx.x >> 6] = s;
    __syncthreads();
    if (threadIdx.x == 0) {
        float tot = 0.0f;
        #pragma unroll
        for (int i = 0; i < 16; ++i) tot += red[i];
        out[0] = 1.0f - tot * (1.0f / 16777216.0f);
    }
}

extern "C" void kernel_launch(void* const* d_in, const int* in_sizes, int n_in,
                              void* d_out, int out_size, void* d_ws, size_t ws_size,
                              hipStream_t stream) {
    const float* x = (const float*)d_in[0];
    const float* y = (const float*)d_in[1];
    float* out     = (float*)d_out;
    float* partial = (float*)d_ws;   // NBLK floats = 32 KB

    dim3 grid(IMG / TS_C, IMG / TS_R, NIMG);   // (8, 16, 64)
    ssim_main<<<grid, 256, 0, stream>>>(x, y, partial);
    ssim_final<<<1, 1024, 0, stream>>>(partial, out);
}